// Round 2
// baseline (476.024 us; speedup 1.0000x reference)
//
#include <hip/hip_runtime.h>

#define NQ 2048
#define NT 131072
#define DD 64
#define MM 1024
#define SUCAP 5120         // per-bucket edge slice cap (mean 3906, sigma 62; +19 sigma)

// Yab[u][0..63] = Xq[u]@Wa ; Yab[u][64..127] = Xq[u]@Wb (interleaved rows: one
// base address per edge in bucket_kernel, both score rows contiguous in L2).
__global__ void yq_kernel(const float* __restrict__ Xq,
                          const float* __restrict__ Wa,
                          const float* __restrict__ Wb,
                          float* __restrict__ Yab) {
    int r = blockIdx.x * 4 + (threadIdx.x >> 6);
    int j = threadIdx.x & 63;
    float sa = 0.f, sb = 0.f;
#pragma unroll
    for (int k = 0; k < DD; ++k) {
        float x = Xq[r * DD + k];
        sa = fmaf(x, Wa[k * DD + j], sa);
        sb = fmaf(x, Wb[k * DD + j], sb);
    }
    Yab[r * 2 * DD + j] = sa;
    Yab[r * 2 * DD + DD + j] = sb;
}

// Pass 1 of global CSR: per-row degree histogram. 4 edges/thread, vectorized
// reads, scattered global atomics (avg 15 hits per counter across whole grid —
// negligible contention; L2 handles the traffic).
__global__ __launch_bounds__(1024) void hist_kernel(const int* __restrict__ v_idx,
                                                    int* __restrict__ hist, int E) {
    int i0 = (blockIdx.x * 1024 + threadIdx.x) * 4;
    if (i0 + 3 < E) {
        int4 v4 = *(const int4*)(v_idx + i0);
        atomicAdd(&hist[v4.x], 1);
        atomicAdd(&hist[v4.y], 1);
        atomicAdd(&hist[v4.z], 1);
        atomicAdd(&hist[v4.w], 1);
    } else {
        for (int j = 0; j < 4; ++j)
            if (i0 + j < E) atomicAdd(&hist[v_idx[i0 + j]], 1);
    }
}

// Pass 2: single-block exclusive scan of hist[NT] -> rofs (CSR offsets) and
// cur (scatter cursors). 4 elems/thread/round, 32 rounds, 3 barriers/round.
__global__ __launch_bounds__(1024) void scan_kernel(const int* __restrict__ hist,
                                                    int* __restrict__ rofs,
                                                    int* __restrict__ cur) {
    __shared__ int wex[16];
    __shared__ int blktot;
    int tid = threadIdx.x, lane = tid & 63, w = tid >> 6;
    int carry = 0;   // uniform: every thread tracks the same running total
    for (int base = 0; base < NT; base += 4096) {
        int4 h = ((const int4*)(hist + base))[tid];
        int s01 = h.x + h.y;
        int sum = s01 + h.z + h.w;
        int incl = sum;
#pragma unroll
        for (int d = 1; d < 64; d <<= 1) {
            int y = __shfl_up(incl, d, 64);
            if (lane >= d) incl += y;
        }
        if (lane == 63) wex[w] = incl;
        __syncthreads();
        if (tid < 16) {
            int t = wex[tid];
            int inc2 = t;
#pragma unroll
            for (int d = 1; d < 16; d <<= 1) {
                int y = __shfl_up(inc2, d, 64);
                if (tid >= d) inc2 += y;
            }
            wex[tid] = inc2 - t;
            if (tid == 15) blktot = inc2;
        }
        __syncthreads();
        int excl = carry + wex[w] + (incl - sum);
        int4 o;
        o.x = excl;
        o.y = excl + h.x;
        o.z = excl + s01;
        o.w = excl + s01 + h.z;
        ((int4*)(rofs + base))[tid] = o;
        ((int4*)(cur + base))[tid] = o;
        carry += blktot;
        __syncthreads();   // wex/blktot reused next round
    }
    if (tid == 0) rofs[NT] = carry;
}

// Pass 3: scatter u into CSR slots. Edges land unordered within a row — fine,
// aggregation is order-independent (no max-subtraction, atomic-free row phase).
__global__ __launch_bounds__(1024) void scatter_kernel(
        const int* __restrict__ u_idx, const int* __restrict__ v_idx,
        int* __restrict__ cur, unsigned short* __restrict__ eu, int E) {
    int i0 = (blockIdx.x * 1024 + threadIdx.x) * 4;
    if (i0 + 3 < E) {
        int4 u4 = *(const int4*)(u_idx + i0);
        int4 v4 = *(const int4*)(v_idx + i0);
        int p0 = atomicAdd(&cur[v4.x], 1);
        int p1 = atomicAdd(&cur[v4.y], 1);
        int p2 = atomicAdd(&cur[v4.z], 1);
        int p3 = atomicAdd(&cur[v4.w], 1);
        eu[p0] = (unsigned short)u4.x;
        eu[p1] = (unsigned short)u4.y;
        eu[p2] = (unsigned short)u4.z;
        eu[p3] = (unsigned short)u4.w;
    } else {
        for (int j = 0; j < 4; ++j) {
            if (i0 + j < E) {
                int pos = atomicAdd(&cur[v_idx[i0 + j]], 1);
                eu[pos] = (unsigned short)u_idx[i0 + j];
            }
        }
    }
}

#define DOT4(a, b) fmaf((a).x, (b).x, fmaf((a).y, (b).y, fmaf((a).z, (b).z, (a).w * (b).w)))

// 16-lane all-reduce sum via DPP adds. bound_ctrl=true lets GCNDPPCombine fuse
// mov_dpp+add into a single v_add_f32_dpp (bc is semantically irrelevant here:
// quad_perm / row_ror source only valid lanes, and all 64 lanes are active at
// every call site — deg branches are wave-uniform, tails gated by a=0 selects).
template <int CTRL>
__device__ __forceinline__ float dpp_add(float x) {
    int xi = __builtin_bit_cast(int, x);
    int yi = __builtin_amdgcn_update_dpp(xi, xi, CTRL, 0xF, 0xF, true);
    return x + __builtin_bit_cast(float, yi);
}
__device__ __forceinline__ float red16(float x) {
    x = dpp_add<0xB1>(x);    // quad_perm [1,0,3,2] : xor 1
    x = dpp_add<0x4E>(x);    // quad_perm [2,3,0,1] : xor 2
    x = dpp_add<0x124>(x);   // row_ror:4
    x = dpp_add<0x128>(x);   // row_ror:8
    return x;
}

// Pure row phase: CSR is prebuilt, so the old hist/scan/LDS-sort collapses to
// one coalesced bulk copy of this bucket's contiguous edge slice into LDS.
// One row per wave, 8 edges/iter (2 per 16-lane group), wave-uniform deg.
__global__ __launch_bounds__(1024, 2) void bucket_kernel(
        const float* __restrict__ Xq,
        const float* __restrict__ Xt,
        const float* __restrict__ Yab,
        const float* __restrict__ ba,
        const float* __restrict__ bb,
        const int* __restrict__ rofs,
        const unsigned short* __restrict__ eu,
        const int* __restrict__ uc,
        float* __restrict__ outXt) {
    __shared__ unsigned short su[SUCAP];
    __shared__ int rstart[257];
    int tid = threadIdx.x;
    int b = blockIdx.x;

    if (tid <= 256) rstart[tid] = rofs[(b << 8) + tid];
    __syncthreads();
    int estart = rstart[0];
    int ecnt = min(rstart[256] - estart, SUCAP);
    for (int i = tid; i < ecnt; i += 1024) su[i] = eu[estart + i];
    __syncthreads();

    int lane = tid & 63;
    int w = tid >> 6;          // wave 0..15
    int l16 = lane & 15;
    int g = lane >> 4;         // group 0..3
    float ba0 = ba[0], bb0 = bb[0];

    for (int r = w; r < 256; r += 16) {
        int v = (b << 8) + r;
        int s0 = rstart[r] - estart;
        int deg = rstart[r + 1] - rstart[r];       // wave-uniform
        deg = min(deg, max(0, ecnt - s0));         // SUCAP guard (never hit in practice)
        if (deg == 0) {
            if (g == 0) {
                float4 o;
                if (v >= NT - MM) {            // consensus row: Xq[uc[i]]
                    int u = uc[v - (NT - MM)];
                    o = ((const float4*)(Xq + (size_t)u * DD))[l16];
                } else {
                    o = ((const float4*)(Xt + (size_t)v * DD))[l16];
                }
                ((float4*)(outXt + (size_t)v * DD))[l16] = o;
            }
            continue;
        }
        float4 xt4 = ((const float4*)(Xt + (size_t)v * DD))[l16];
        float4 acc = make_float4(0.f, 0.f, 0.f, 0.f);
        float s = 0.f;
        for (int base = 0; base < deg; base += 8) {
            int e0 = base + g;
            int e1 = base + 4 + g;
            bool ok0 = e0 < deg, ok1 = e1 < deg;
            int u0 = (int)su[s0 + (ok0 ? e0 : 0)];
            int u1 = (int)su[s0 + (ok1 ? e1 : 0)];
            const float4* Y0 = (const float4*)(Yab + u0 * (2 * DD));
            const float4* Y1 = (const float4*)(Yab + u1 * (2 * DD));
            float4 ya0 = Y0[l16], yb0 = Y0[16 + l16];
            float4 ya1 = Y1[l16], yb1 = Y1[16 + l16];
            float pa0 = DOT4(ya0, xt4), pb0 = DOT4(yb0, xt4);
            float pa1 = DOT4(ya1, xt4), pb1 = DOT4(yb1, xt4);
            pa0 = red16(pa0); pb0 = red16(pb0);
            pa1 = red16(pa1); pb1 = red16(pb1);
            float la0 = pa0 + ba0, la1 = pa1 + ba0;
            float t0 = __expf(la0), t1 = __expf(la1);
            float al0 = la0 > 0.f ? la0 : (t0 - 1.f);
            float al1 = la1 > 0.f ? la1 : (t1 - 1.f);
            float a0 = ok0 ? __expf(al0) : 0.f;   // gate tail edges to zero weight
            float a1 = ok1 ? __expf(al1) : 0.f;
            float be0 = __builtin_amdgcn_rcpf(1.f + __expf(-(pb0 + bb0)));
            float be1 = __builtin_amdgcn_rcpf(1.f + __expf(-(pb1 + bb0)));
            float4 xq0 = ((const float4*)(Xq + (size_t)u0 * DD))[l16];
            float4 xq1 = ((const float4*)(Xq + (size_t)u1 * DD))[l16];
            float4 h0, h1;
            h0.x = fmaf(be0, xt4.x - xq0.x, xq0.x);
            h0.y = fmaf(be0, xt4.y - xq0.y, xq0.y);
            h0.z = fmaf(be0, xt4.z - xq0.z, xq0.z);
            h0.w = fmaf(be0, xt4.w - xq0.w, xq0.w);
            h1.x = fmaf(be1, xt4.x - xq1.x, xq1.x);
            h1.y = fmaf(be1, xt4.y - xq1.y, xq1.y);
            h1.z = fmaf(be1, xt4.z - xq1.z, xq1.z);
            h1.w = fmaf(be1, xt4.w - xq1.w, xq1.w);
            acc.x = fmaf(a0, h0.x, fmaf(a1, h1.x, acc.x));
            acc.y = fmaf(a0, h0.y, fmaf(a1, h1.y, acc.y));
            acc.z = fmaf(a0, h0.z, fmaf(a1, h1.z, acc.z));
            acc.w = fmaf(a0, h0.w, fmaf(a1, h1.w, acc.w));
            s += a0 + a1;
        }
        // combine 4 groups: lanes {l, l+16, l+32, l+48} hold partials of the
        // same feature. Two xor levels give all lanes the totals.
        acc.x += __shfl_xor(acc.x, 16, 64);
        acc.y += __shfl_xor(acc.y, 16, 64);
        acc.z += __shfl_xor(acc.z, 16, 64);
        acc.w += __shfl_xor(acc.w, 16, 64);
        s     += __shfl_xor(s, 16, 64);
        acc.x += __shfl_xor(acc.x, 32, 64);
        acc.y += __shfl_xor(acc.y, 32, 64);
        acc.z += __shfl_xor(acc.z, 32, 64);
        acc.w += __shfl_xor(acc.w, 32, 64);
        s     += __shfl_xor(s, 32, 64);
        if (g == 0) {
            float inv = __builtin_amdgcn_rcpf(s);
            float4 o = make_float4(acc.x * inv, acc.y * inv, acc.z * inv, acc.w * inv);
            ((float4*)(outXt + (size_t)v * DD))[l16] = o;
        }
    }
}

extern "C" void kernel_launch(void* const* d_in, const int* in_sizes, int n_in,
                              void* d_out, int out_size, void* d_ws, size_t ws_size,
                              hipStream_t stream) {
    const float* Xq = (const float*)d_in[0];
    const float* Xt = (const float*)d_in[1];
    const float* Wa = (const float*)d_in[2];
    const float* ba = (const float*)d_in[3];
    const float* Wb = (const float*)d_in[4];
    const float* bb = (const float*)d_in[5];
    const int* u_idx = (const int*)d_in[6];
    const int* v_idx = (const int*)d_in[7];
    const int* uc = (const int*)d_in[8];
    const int* vc = (const int*)d_in[9];
    const int E = in_sizes[6];
    (void)vc;

    float* out = (float*)d_out;
    float* outXq = out;                 // NQ*DD
    float* outXt = out + NQ * DD;       // NT*DD

    char* ws = (char*)d_ws;
    float* Yab = (float*)ws;            ws += (size_t)NQ * 2 * DD * sizeof(float);   // 1M
    int* hist = (int*)ws;               ws += (size_t)NT * sizeof(int);              // 512K
    int* rofs = (int*)ws;               ws += (size_t)(NT + 1) * sizeof(int);        // 512K
    ws = (char*)(((size_t)ws + 255) & ~(size_t)255);
    int* cur = (int*)ws;                ws += (size_t)NT * sizeof(int);              // 512K
    unsigned short* eu = (unsigned short*)ws;  ws += (size_t)(E + 4) * sizeof(unsigned short); // 4M

    // Output 0 is Xq unchanged.
    hipMemcpyAsync(outXq, Xq, NQ * DD * sizeof(float), hipMemcpyDeviceToDevice, stream);
    hipMemsetAsync(hist, 0, (size_t)NT * sizeof(int), stream);

    yq_kernel<<<NQ / 4, 256, 0, stream>>>(Xq, Wa, Wb, Yab);

    int nblk = (E + 4095) / 4096;
    hist_kernel<<<nblk, 1024, 0, stream>>>(v_idx, hist, E);
    scan_kernel<<<1, 1024, 0, stream>>>(hist, rofs, cur);
    scatter_kernel<<<nblk, 1024, 0, stream>>>(u_idx, v_idx, cur, eu, E);

    bucket_kernel<<<NT / 256, 1024, 0, stream>>>(Xq, Xt, Yab, ba, bb, rofs, eu,
                                                 uc, outXt);
}